// Round 11
// baseline (549.521 us; speedup 1.0000x reference)
//
#include <hip/hip_runtime.h>
#include <hip/hip_bf16.h>

#define NSENT 4000
#define LSEQ  128
#define VEC   50
#define POS   5
#define EMBD  60      // VEC + 2*POS
#define HIDD  230
#define HSTR  232     // padded channel stride for H
#define NBAG  500
#define NREL  25
#define NTILEP 16     // padded N-tile count (15 real, tile 15 = zeros)
#define KSTEPS 6      // K = 192 (3 taps * 64 e-slots), 6 MFMA K-steps of 32
#define ESTR  72      // LDS row stride in bf16 shorts (144 B)
#define SLOTS 130     // l+1 shift; rows 0/129 are SAME-pad zeros

// e-slot mapping (A and B MUST agree):
//   e 0..49  = wemb dims 0..49      (e50,51 = 0)
//   e 52..55 = p1 dims 0..3
//   e 56..59 = p2 dims 0..3
//   e 60     = p1 dim 4, e61 = 0
//   e 62     = p2 dim 4, e63 = 0
typedef __attribute__((ext_vector_type(8))) short short8;   // 8 bf16 = 4 VGPRs
typedef __attribute__((ext_vector_type(4))) float f32x4;

__device__ __forceinline__ unsigned short f2bf(float f) {
    union { float f; unsigned u; } v; v.f = f;
    unsigned u = v.u + 0x7FFF + ((v.u >> 16) & 1);   // RNE
    return (unsigned short)(u >> 16);
}

// packed f32x2 -> bf16x2 (v_cvt_pk_bf16_f32 on gfx950), low short = first arg
__device__ __forceinline__ unsigned pk(float a, float b) {
    __hip_bfloat162 h = __float22bfloat162_rn(float2{a, b});
    union { __hip_bfloat162 h; unsigned u; } c; c.h = h;
    return c.u;
}

// ---- prep: conv_w [HID][EMB][3] -> Bfrag[ntile][kstep][lane][8] (bf16) ----
// B layout for mfma_f32_16x16x32_bf16: B[n = lane&15][k = (lane>>4)*8 + j]
__global__ __launch_bounds__(256) void prep_b(const float* __restrict__ conv_w,
                                              unsigned short* __restrict__ Bfrag) {
    int idx = blockIdx.x * 256 + threadIdx.x;
    if (idx >= NTILEP * KSTEPS * 64 * 8) return;
    int j    = idx & 7;
    int lane = (idx >> 3) & 63;
    int t    = idx >> 9;
    int ks   = t % KSTEPS;
    int nt   = t / KSTEPS;
    int c    = nt * 16 + (lane & 15);
    int klin = ks * 32 + (lane >> 4) * 8 + j;
    int tap  = klin >> 6;
    int e    = klin & 63;
    float v  = 0.f;
    if (c < HIDD) {
        int eidx = -1;
        if (e < 50)                 eidx = e;             // wemb dims
        else if (e >= 52 && e < 56) eidx = 50 + (e - 52); // p1[0..3]
        else if (e >= 56 && e < 60) eidx = 55 + (e - 56); // p2[0..3]
        else if (e == 60)           eidx = 54;            // p1[4]
        else if (e == 62)           eidx = 59;            // p2[4]
        if (eidx >= 0) v = conv_w[(c * EMBD + eidx) * 3 + tap];
    }
    Bfrag[idx] = f2bf(v);
}

// ---- Kernel 2: gather(+cvt) + conv1d(k=3,SAME) via bf16 MFMA + maxpool + relu ----
// block = 256 thr = 4 waves, ONE sentence (grid 4000, 20.5 KB LDS -> 6-7
// blocks/CU co-resident so prologue bubbles overlap across blocks).
// The 15 N-tiles are covered in TWO sequential halves (unroll 1): wave w in
// half h owns tiles {h*8+2w, h*8+2w+1}; B (48 VGPRs) reloaded per half.
// Per-iteration liveness = R9-proven budget (B48+acc8+maxv8 -> VGPR ~64).
// A-frag A[m=lane&15][k=quad*8+j] from LDS; C tile col=lane&15, row=quad*4+reg
__global__ __launch_bounds__(256, 4) void encoder(
    const int*   __restrict__ X,  const int* __restrict__ P1, const int* __restrict__ P2,
    const float* __restrict__ wemb, const float* __restrict__ p1emb, const float* __restrict__ p2emb,
    const unsigned short* __restrict__ Bfrag, const float* __restrict__ conv_b,
    float* __restrict__ H)
{
    __shared__ unsigned short embS[SLOTS * ESTR];   // [slot][e] bf16
    __shared__ int xS[LSEQ], p1S[LSEQ], p2S[LSEQ];
    const int n = blockIdx.x, tid = threadIdx.x;
    const int lane = tid & 63;
    const int wave = __builtin_amdgcn_readfirstlane(tid >> 6);
    const int m    = lane & 15;
    const int quad = lane >> 4;

    // ---- stage index rows + zero pad rows (slots 0, 129)
    for (int i = tid; i < 3 * LSEQ; i += 256) {
        int which = i >> 7, l = i & 127;
        const int* src = (which == 0) ? X : (which == 1) ? P1 : P2;
        int v = src[(size_t)n * LSEQ + l];
        int* dst = (which == 0) ? xS : (which == 1) ? p1S : p2S;
        dst[l] = v;
    }
    if (tid < 64) {
        int r = (tid & 32) ? (SLOTS - 1) : 0;
        *(unsigned*)(embS + r * ESTR + (tid & 31) * 2) = 0u;
    }
    __syncthreads();

    // ---- gather: 16 lanes per token, f32 loads + packed cvt, 8B LDS writes
    #pragma unroll
    for (int it = 0; it < (LSEQ * 16) / 256; ++it) {
        int i = tid + it * 256;
        int l = i >> 4, j = i & 15;
        unsigned short* dst = embS + (l + 1) * ESTR;
        uint2 v;
        if (j < 13) {                 // e 4j..4j+3 from wemb (200 B rows, 8B-aligned)
            const float* src = wemb + (size_t)xS[l] * VEC + j * 4;
            float2 fa = *(const float2*)(src);
            float a2 = 0.f, a3 = 0.f;
            if (j < 12) { float2 fb = *(const float2*)(src + 2); a2 = fb.x; a3 = fb.y; }
            v.x = pk(fa.x, fa.y); v.y = pk(a2, a3);
        } else if (j == 13) {         // p1[0..3] -> e52..55
            const float* p = p1emb + p1S[l] * POS;
            v.x = pk(p[0], p[1]); v.y = pk(p[2], p[3]);
        } else if (j == 14) {         // p2[0..3] -> e56..59
            const float* p = p2emb + p2S[l] * POS;
            v.x = pk(p[0], p[1]); v.y = pk(p[2], p[3]);
        } else {                      // tails -> e60..63
            float a = p1emb[p1S[l] * POS + 4];
            float b = p2emb[p2S[l] * POS + 4];
            v.x = pk(a, 0.f); v.y = pk(b, 0.f);
        }
        *(uint2*)(dst + (j < 13 ? j * 4 : 52 + (j - 13) * 4)) = v;
    }
    __syncthreads();

    // ---- two N-tile halves sequentially; per-half liveness = R9 budget
    #pragma unroll 1
    for (int h = 0; h < 2; ++h) {
        const int nt0 = h * 8 + wave * 2;

        // this wave's B fragments for this half -> registers (48 VGPRs)
        short8 Bw[2][KSTEPS];
        #pragma unroll
        for (int t = 0; t < 2; ++t)
            #pragma unroll
            for (int ks = 0; ks < KSTEPS; ++ks)
                Bw[t][ks] = *(const short8*)(Bfrag +
                    ((size_t)((nt0 + t) * KSTEPS + ks) * 64 + lane) * 8);

        float maxv[2][4];
        #pragma unroll
        for (int t = 0; t < 2; ++t)
            #pragma unroll
            for (int r = 0; r < 4; ++r) maxv[t][r] = -1e30f;

        #pragma unroll
        for (int mt = 0; mt < 8; ++mt) {
            short8 A[KSTEPS];
            #pragma unroll
            for (int ks = 0; ks < KSTEPS; ++ks) {
                int tap = ks >> 1;
                int col = (ks & 1) * 32 + quad * 8;
                int row = mt * 16 + m + tap;        // slot (l+tap), +1 shift folded in
                A[ks] = *(const short8*)(embS + row * ESTR + col);
            }
            f32x4 acc[2];
            #pragma unroll
            for (int t = 0; t < 2; ++t) acc[t] = (f32x4){0.f, 0.f, 0.f, 0.f};
            #pragma unroll
            for (int ks = 0; ks < KSTEPS; ++ks)
                #pragma unroll
                for (int t = 0; t < 2; ++t)
                    acc[t] = __builtin_amdgcn_mfma_f32_16x16x32_bf16(A[ks], Bw[t][ks], acc[t], 0, 0, 0);
            #pragma unroll
            for (int t = 0; t < 2; ++t)
                #pragma unroll
                for (int r = 0; r < 4; ++r)
                    maxv[t][r] = fmaxf(maxv[t][r], acc[t][r]);
        }

        // reduce rows (4 regs, then quads via xor 16/32) -> bias + relu -> H
        #pragma unroll
        for (int t = 0; t < 2; ++t) {
            float v = fmaxf(fmaxf(maxv[t][0], maxv[t][1]),
                            fmaxf(maxv[t][2], maxv[t][3]));
            v = fmaxf(v, __shfl_xor(v, 16));
            v = fmaxf(v, __shfl_xor(v, 32));
            int c = (nt0 + t) * 16 + lane;
            if (lane < 16 && c < HIDD)
                H[(size_t)n * HSTR + c] = fmaxf(v + conv_b[c], 0.f);
        }
    }
}

// ---- Kernel 3: one wave per bag, zero barriers, all state in registers ----
__global__ __launch_bounds__(64) void attn(
    const float* __restrict__ H, const float* __restrict__ rel_w, const float* __restrict__ rel_b,
    const int* __restrict__ relation, const int* __restrict__ scope,
    float* __restrict__ out)
{
    const int b = blockIdx.x, lane = threadIdx.x;
    const int start = scope[2 * b];
    int ns = scope[2 * b + 1] - start;
    if (ns > 8) ns = 8;
    const int rel = relation[b];

    float q[4], h[8][4];
    #pragma unroll
    for (int k = 0; k < 4; ++k) {
        int c = lane + 64 * k;
        q[k] = (c < HIDD) ? rel_w[rel * HIDD + c] : 0.f;
    }
    #pragma unroll
    for (int s = 0; s < 8; ++s)
        #pragma unroll
        for (int k = 0; k < 4; ++k) {
            int c = lane + 64 * k;
            h[s][k] = (s < ns && c < HIDD) ? H[(size_t)(start + s) * HSTR + c] : 0.f;
        }

    float logit[8];
    #pragma unroll
    for (int s = 0; s < 8; ++s) {
        float t = q[0] * h[s][0] + q[1] * h[s][1] + q[2] * h[s][2] + q[3] * h[s][3];
        #pragma unroll
        for (int off = 32; off > 0; off >>= 1) t += __shfl_xor(t, off);
        logit[s] = t;   // all lanes hold it
    }

    float mx = -1e30f;
    for (int s = 0; s < ns; ++s) mx = fmaxf(mx, logit[s]);
    float a[8], den = 0.f;
    #pragma unroll
    for (int s = 0; s < 8; ++s) { a[s] = (s < ns) ? expf(logit[s] - mx) : 0.f; den += a[s]; }
    float inv = 1.f / den;

    float rep[4];
    #pragma unroll
    for (int k = 0; k < 4; ++k) {
        float r = 0.f;
        #pragma unroll
        for (int s = 0; s < 8; ++s) r += a[s] * h[s][k];
        rep[k] = r * inv;
    }

    // classifier: 25 rows of rel_w, coalesced wave reads (L2-broadcast)
    #pragma unroll 5
    for (int g = 0; g < NREL; ++g) {
        float t = 0.f;
        #pragma unroll
        for (int k = 0; k < 4; ++k) {
            int c = lane + 64 * k;
            t += (c < HIDD) ? rel_w[g * HIDD + c] * rep[k] : 0.f;
        }
        #pragma unroll
        for (int off = 32; off > 0; off >>= 1) t += __shfl_xor(t, off);
        if (lane == 0) out[b * NREL + g] = t + rel_b[g];
    }
}

extern "C" void kernel_launch(void* const* d_in, const int* in_sizes, int n_in,
                              void* d_out, int out_size, void* d_ws, size_t ws_size,
                              hipStream_t stream) {
    const int*   X        = (const int*)d_in[0];
    const int*   P1       = (const int*)d_in[1];
    const int*   P2       = (const int*)d_in[2];
    const int*   scope    = (const int*)d_in[5];
    const int*   relation = (const int*)d_in[6];
    const float* wemb     = (const float*)d_in[7];
    const float* p1emb    = (const float*)d_in[8];
    const float* p2emb    = (const float*)d_in[9];
    const float* conv_w   = (const float*)d_in[10];
    const float* conv_b   = (const float*)d_in[11];
    const float* rel_w    = (const float*)d_in[12];
    const float* rel_b    = (const float*)d_in[13];

    // workspace layout
    char* ws = (char*)d_ws;
    float* H = (float*)ws;                                   // 4000*232*4 = 3,712,000
    size_t off = (size_t)NSENT * HSTR * 4;
    unsigned short* Bfrag = (unsigned short*)(ws + off);     // 16*6*64*8*2 = 98,304

    const int btot = NTILEP * KSTEPS * 64 * 8;
    hipLaunchKernelGGL(prep_b, dim3((btot + 255) / 256), dim3(256), 0, stream,
                       conv_w, Bfrag);
    hipLaunchKernelGGL(encoder, dim3(NSENT), dim3(256), 0, stream,
                       X, P1, P2, wemb, p1emb, p2emb, Bfrag, conv_b, H);
    hipLaunchKernelGGL(attn, dim3(NBAG), dim3(64), 0, stream,
                       H, rel_w, rel_b, relation, scope, (float*)d_out);
}

// Round 12
// 183.552 us; speedup vs baseline: 2.9938x; 2.9938x over previous
//
#include <hip/hip_runtime.h>
#include <hip/hip_bf16.h>

#define NSENT 4000
#define LSEQ  128
#define VEC   50
#define POS   5
#define EMBD  60      // VEC + 2*POS
#define HIDD  230
#define HSTR  232     // padded channel stride for H
#define NBAG  500
#define NREL  25
#define NTILEP 16     // padded N-tile count (15 real, tile 15 = zeros)
#define KSTEPS 6      // K = 192 (3 taps * 64 e-slots), 6 MFMA K-steps of 32
#define ESTR  72      // LDS row stride in bf16 shorts (144 B; row step = 4 banks)
#define SLOTS 130     // l+1 shift; rows 0/129 are SAME-pad zeros
#define SSTR  (SLOTS * ESTR)   // per-sentence LDS half

// e-slot mapping (A and B MUST agree):
//   e 0..49  = wemb dims 0..49      (e50,51 = 0)
//   e 52..55 = p1 dims 0..3
//   e 56..59 = p2 dims 0..3
//   e 60     = p1 dim 4, e61 = 0
//   e 62     = p2 dim 4, e63 = 0
typedef __attribute__((ext_vector_type(8))) short short8;   // 8 bf16 = 4 VGPRs
typedef __attribute__((ext_vector_type(4))) float f32x4;

__device__ __forceinline__ unsigned short f2bf(float f) {
    union { float f; unsigned u; } v; v.f = f;
    unsigned u = v.u + 0x7FFF + ((v.u >> 16) & 1);   // RNE
    return (unsigned short)(u >> 16);
}

// packed f32x2 -> bf16x2 (v_cvt_pk_bf16_f32 on gfx950), low short = first arg
__device__ __forceinline__ unsigned pk(float a, float b) {
    __hip_bfloat162 h = __float22bfloat162_rn(float2{a, b});
    union { __hip_bfloat162 h; unsigned u; } c; c.h = h;
    return c.u;
}

// ---- prep: conv_w [HID][EMB][3] -> Bfrag[ntile][kstep][lane][8] (bf16) ----
// B layout for mfma_f32_16x16x32_bf16: B[n = lane&15][k = (lane>>4)*8 + j]
__global__ __launch_bounds__(256) void prep_b(const float* __restrict__ conv_w,
                                              unsigned short* __restrict__ Bfrag) {
    int idx = blockIdx.x * 256 + threadIdx.x;
    if (idx >= NTILEP * KSTEPS * 64 * 8) return;
    int j    = idx & 7;
    int lane = (idx >> 3) & 63;
    int t    = idx >> 9;
    int ks   = t % KSTEPS;
    int nt   = t / KSTEPS;
    int c    = nt * 16 + (lane & 15);
    int klin = ks * 32 + (lane >> 4) * 8 + j;
    int tap  = klin >> 6;
    int e    = klin & 63;
    float v  = 0.f;
    if (c < HIDD) {
        int eidx = -1;
        if (e < 50)                 eidx = e;             // wemb dims
        else if (e >= 52 && e < 56) eidx = 50 + (e - 52); // p1[0..3]
        else if (e >= 56 && e < 60) eidx = 55 + (e - 56); // p2[0..3]
        else if (e == 60)           eidx = 54;            // p1[4]
        else if (e == 62)           eidx = 59;            // p2[4]
        if (eidx >= 0) v = conv_w[(c * EMBD + eidx) * 3 + tap];
    }
    Bfrag[idx] = f2bf(v);
}

// ---- Kernel 2: gather(+cvt) + conv1d(k=3,SAME) via bf16 MFMA + maxpool + relu ----
// one block = 512 thr = 8 waves handles TWO sentences (grid 2000), sentences
// computed SEQUENTIALLY (#pragma unroll 1) so per-iteration liveness equals
// the proven budget (B48+acc8+maxv8, fits 64 VGPR without spilling).
// R5/R8/R10/R11 all showed ANY deviation from this structure triggers either
// a 64-VGPR rollback with B-refetch or catastrophic scratch spill. Do not
// perturb: B-load at kernel top, 8-mt inner loop, sentence-sequential outer.
// wave w owns N-tiles {2w, 2w+1} for both sentences.
// A-frag A[m=lane&15][k=quad*8+j] from LDS; C tile col=lane&15, row=quad*4+reg
__global__ __launch_bounds__(512, 4) void encoder(
    const int*   __restrict__ X,  const int* __restrict__ P1, const int* __restrict__ P2,
    const float* __restrict__ wemb, const float* __restrict__ p1emb, const float* __restrict__ p2emb,
    const unsigned short* __restrict__ Bfrag, const float* __restrict__ conv_b,
    float* __restrict__ H)
{
    __shared__ unsigned short embS[2 * SSTR];   // [sent][slot][e] bf16
    __shared__ int xS[2 * LSEQ], p1S[2 * LSEQ], p2S[2 * LSEQ];
    const int b2 = blockIdx.x * 2, tid = threadIdx.x;
    const int lane = tid & 63;
    const int wave = __builtin_amdgcn_readfirstlane(tid >> 6);
    const int nt0  = wave * 2;
    const int m    = lane & 15;
    const int quad = lane >> 4;

    // ---- this wave's B fragments -> registers (48 VGPRs), issued first
    short8 Bw[2][KSTEPS];
    #pragma unroll
    for (int t = 0; t < 2; ++t)
        #pragma unroll
        for (int ks = 0; ks < KSTEPS; ++ks)
            Bw[t][ks] = *(const short8*)(Bfrag + ((size_t)((nt0 + t) * KSTEPS + ks) * 64 + lane) * 8);

    // ---- stage index rows (both sentences contiguous) + zero pad rows
    #pragma unroll
    for (int it = 0; it < 2; ++it) {
        int i = tid + it * 512;
        if (i < 768) {
            int which = i >> 8, l2 = i & 255;
            const int* src = (which == 0) ? X : (which == 1) ? P1 : P2;
            int v = src[(size_t)b2 * LSEQ + l2];
            int* dst = (which == 0) ? xS : (which == 1) ? p1S : p2S;
            dst[l2] = v;
        } else {
            int t = i - 768;     // 128 dword-writes: 2 sent x 2 pad rows x 64 shorts
            if (t < 128) {
                int sent = t >> 6;
                int r = (t & 32) ? (SLOTS - 1) : 0;
                *(unsigned*)(embS + sent * SSTR + r * ESTR + (t & 31) * 2) = 0u;
            }
        }
    }
    __syncthreads();

    // ---- gather both sentences: 16 lanes/token, f32 loads + packed cvt, 8B writes
    #pragma unroll
    for (int it = 0; it < (2 * LSEQ * 16) / 512; ++it) {
        int i = tid + it * 512;
        int sent = i >> 11, rem = i & 2047;
        int l = rem >> 4, j = rem & 15;
        int li = sent * LSEQ + l;
        unsigned short* dst = embS + sent * SSTR + (l + 1) * ESTR;
        uint2 v;
        if (j < 13) {                 // e 4j..4j+3 from wemb (200 B rows, 8B-aligned)
            const float* src = wemb + (size_t)xS[li] * VEC + j * 4;
            float2 fa = *(const float2*)(src);
            float a2 = 0.f, a3 = 0.f;
            if (j < 12) { float2 fb = *(const float2*)(src + 2); a2 = fb.x; a3 = fb.y; }
            v.x = pk(fa.x, fa.y); v.y = pk(a2, a3);
        } else if (j == 13) {         // p1[0..3] -> e52..55
            const float* p = p1emb + p1S[li] * POS;
            v.x = pk(p[0], p[1]); v.y = pk(p[2], p[3]);
        } else if (j == 14) {         // p2[0..3] -> e56..59
            const float* p = p2emb + p2S[li] * POS;
            v.x = pk(p[0], p[1]); v.y = pk(p[2], p[3]);
        } else {                      // tails -> e60..63
            float a = p1emb[p1S[li] * POS + 4];
            float b = p2emb[p2S[li] * POS + 4];
            v.x = pk(a, 0.f); v.y = pk(b, 0.f);
        }
        *(uint2*)(dst + (j < 13 ? j * 4 : 52 + (j - 13) * 4)) = v;
    }
    __syncthreads();

    // ---- sentences sequentially: live state per iteration = proven budget
    #pragma unroll 1
    for (int s = 0; s < 2; ++s) {
        const unsigned short* eb = embS + s * SSTR;
        float maxv[2][4];
        #pragma unroll
        for (int t = 0; t < 2; ++t)
            #pragma unroll
            for (int r = 0; r < 4; ++r) maxv[t][r] = -1e30f;

        #pragma unroll
        for (int mt = 0; mt < 8; ++mt) {
            short8 A[KSTEPS];
            #pragma unroll
            for (int ks = 0; ks < KSTEPS; ++ks) {
                int tap = ks >> 1;
                int col = (ks & 1) * 32 + quad * 8;
                int row = mt * 16 + m + tap;        // slot (l+tap), +1 shift folded in
                A[ks] = *(const short8*)(eb + row * ESTR + col);
            }
            f32x4 acc[2];
            #pragma unroll
            for (int t = 0; t < 2; ++t) acc[t] = (f32x4){0.f, 0.f, 0.f, 0.f};
            #pragma unroll
            for (int ks = 0; ks < KSTEPS; ++ks)
                #pragma unroll
                for (int t = 0; t < 2; ++t)
                    acc[t] = __builtin_amdgcn_mfma_f32_16x16x32_bf16(A[ks], Bw[t][ks], acc[t], 0, 0, 0);
            #pragma unroll
            for (int t = 0; t < 2; ++t)
                #pragma unroll
                for (int r = 0; r < 4; ++r)
                    maxv[t][r] = fmaxf(maxv[t][r], acc[t][r]);
        }

        // reduce rows (4 regs, then quads via xor 16/32) -> bias + relu -> H
        #pragma unroll
        for (int t = 0; t < 2; ++t) {
            float v = fmaxf(fmaxf(maxv[t][0], maxv[t][1]),
                            fmaxf(maxv[t][2], maxv[t][3]));
            v = fmaxf(v, __shfl_xor(v, 16));
            v = fmaxf(v, __shfl_xor(v, 32));
            int c = (nt0 + t) * 16 + lane;
            if (lane < 16 && c < HIDD)
                H[(size_t)(b2 + s) * HSTR + c] = fmaxf(v + conv_b[c], 0.f);
        }
    }
}

// ---- Kernel 3: one wave per bag, zero barriers, all state in registers ----
__global__ __launch_bounds__(64) void attn(
    const float* __restrict__ H, const float* __restrict__ rel_w, const float* __restrict__ rel_b,
    const int* __restrict__ relation, const int* __restrict__ scope,
    float* __restrict__ out)
{
    const int b = blockIdx.x, lane = threadIdx.x;
    const int start = scope[2 * b];
    int ns = scope[2 * b + 1] - start;
    if (ns > 8) ns = 8;
    const int rel = relation[b];

    float q[4], h[8][4];
    #pragma unroll
    for (int k = 0; k < 4; ++k) {
        int c = lane + 64 * k;
        q[k] = (c < HIDD) ? rel_w[rel * HIDD + c] : 0.f;
    }
    #pragma unroll
    for (int s = 0; s < 8; ++s)
        #pragma unroll
        for (int k = 0; k < 4; ++k) {
            int c = lane + 64 * k;
            h[s][k] = (s < ns && c < HIDD) ? H[(size_t)(start + s) * HSTR + c] : 0.f;
        }

    float logit[8];
    #pragma unroll
    for (int s = 0; s < 8; ++s) {
        float t = q[0] * h[s][0] + q[1] * h[s][1] + q[2] * h[s][2] + q[3] * h[s][3];
        #pragma unroll
        for (int off = 32; off > 0; off >>= 1) t += __shfl_xor(t, off);
        logit[s] = t;   // all lanes hold it
    }

    float mx = -1e30f;
    for (int s = 0; s < ns; ++s) mx = fmaxf(mx, logit[s]);
    float a[8], den = 0.f;
    #pragma unroll
    for (int s = 0; s < 8; ++s) { a[s] = (s < ns) ? expf(logit[s] - mx) : 0.f; den += a[s]; }
    float inv = 1.f / den;

    float rep[4];
    #pragma unroll
    for (int k = 0; k < 4; ++k) {
        float r = 0.f;
        #pragma unroll
        for (int s = 0; s < 8; ++s) r += a[s] * h[s][k];
        rep[k] = r * inv;
    }

    // classifier: 25 rows of rel_w, coalesced wave reads (L2-broadcast)
    #pragma unroll 5
    for (int g = 0; g < NREL; ++g) {
        float t = 0.f;
        #pragma unroll
        for (int k = 0; k < 4; ++k) {
            int c = lane + 64 * k;
            t += (c < HIDD) ? rel_w[g * HIDD + c] * rep[k] : 0.f;
        }
        #pragma unroll
        for (int off = 32; off > 0; off >>= 1) t += __shfl_xor(t, off);
        if (lane == 0) out[b * NREL + g] = t + rel_b[g];
    }
}

extern "C" void kernel_launch(void* const* d_in, const int* in_sizes, int n_in,
                              void* d_out, int out_size, void* d_ws, size_t ws_size,
                              hipStream_t stream) {
    const int*   X        = (const int*)d_in[0];
    const int*   P1       = (const int*)d_in[1];
    const int*   P2       = (const int*)d_in[2];
    const int*   scope    = (const int*)d_in[5];
    const int*   relation = (const int*)d_in[6];
    const float* wemb     = (const float*)d_in[7];
    const float* p1emb    = (const float*)d_in[8];
    const float* p2emb    = (const float*)d_in[9];
    const float* conv_w   = (const float*)d_in[10];
    const float* conv_b   = (const float*)d_in[11];
    const float* rel_w    = (const float*)d_in[12];
    const float* rel_b    = (const float*)d_in[13];

    // workspace layout
    char* ws = (char*)d_ws;
    float* H = (float*)ws;                                   // 4000*232*4 = 3,712,000
    size_t off = (size_t)NSENT * HSTR * 4;
    unsigned short* Bfrag = (unsigned short*)(ws + off);     // 16*6*64*8*2 = 98,304

    const int btot = NTILEP * KSTEPS * 64 * 8;
    hipLaunchKernelGGL(prep_b, dim3((btot + 255) / 256), dim3(256), 0, stream,
                       conv_w, Bfrag);
    hipLaunchKernelGGL(encoder, dim3(NSENT / 2), dim3(512), 0, stream,
                       X, P1, P2, wemb, p1emb, p2emb, Bfrag, conv_b, H);
    hipLaunchKernelGGL(attn, dim3(NBAG), dim3(64), 0, stream,
                       H, rel_w, rel_b, relation, scope, (float*)d_out);
}